// Round 4
// baseline (58.450 us; speedup 1.0000x reference)
//
#include <hip/hip_runtime.h>
#include <math.h>

#define NE 4096
#define NROWS_STATE 160   // 5 * 32 layers

// ws layout (floats)
#define WS_XK   0
#define WS_XV   (NE)
#define WS_XR   (2*NE)
#define WS_KK   (3*NE)
#define WS_VV   (4*NE)
#define WS_RR   (5*NE)
#define WS_RWKV (6*NE)

__device__ __forceinline__ float wave_reduce_sum(float v) {
    #pragma unroll
    for (int off = 32; off > 0; off >>= 1)
        v += __shfl_down(v, off, 64);
    return v;  // valid in lane 0
}

// ---------------- kernel 1: state copy (skipping written rows) + LN + time-mix ----------------
__global__ void __launch_bounds__(256)
k_copy_ln_mix(const float* __restrict__ in, const float* __restrict__ state,
              const float* __restrict__ tmk, const float* __restrict__ tmv,
              const float* __restrict__ tmr, const float* __restrict__ lnw,
              const float* __restrict__ lnb, const int* __restrict__ layer,
              float* __restrict__ out_state, float* __restrict__ ws) {
    int li = layer[0];
    if (blockIdx.x != 0) {
        int i4 = (blockIdx.x - 1) * 256 + threadIdx.x;   // float4 index, 1024 per row
        int row = i4 >> 10;
        if (row < 5 * li + 1 || row > 5 * li + 4) {
            ((float4*)out_state)[i4] = ((const float4*)state)[i4];
        }
        return;
    }
    __shared__ float sm1[4];
    __shared__ float sm2[4];
    __shared__ float s_mu, s_rstd;
    int t = threadIdx.x;
    int lane = t & 63, wid = t >> 6;

    float4 v[4];
    float sum = 0.0f, sumsq = 0.0f;
    #pragma unroll
    for (int j = 0; j < 4; ++j) {
        v[j] = ((const float4*)in)[t * 4 + j];
        sum   += v[j].x + v[j].y + v[j].z + v[j].w;
        sumsq += v[j].x*v[j].x + v[j].y*v[j].y + v[j].z*v[j].z + v[j].w*v[j].w;
    }
    float s1 = wave_reduce_sum(sum);
    float s2 = wave_reduce_sum(sumsq);
    if (lane == 0) { sm1[wid] = s1; sm2[wid] = s2; }
    __syncthreads();
    if (t == 0) {
        float tot = sm1[0] + sm1[1] + sm1[2] + sm1[3];
        float tot2 = sm2[0] + sm2[1] + sm2[2] + sm2[3];
        float mu  = tot * (1.0f / NE);
        float var = tot2 * (1.0f / NE) - mu * mu;
        s_mu = mu;
        s_rstd = rsqrtf(var + 1e-5f);
    }
    __syncthreads();
    float mu = s_mu, rstd = s_rstd;

    const float* prev_row = state + (size_t)(5 * li + 1) * NE;
    float* x_row = out_state + (size_t)(5 * li + 1) * NE;

    #pragma unroll
    for (int j = 0; j < 4; ++j) {
        #pragma unroll
        for (int c = 0; c < 4; ++c) {
            int idx = t * 16 + j * 4 + c;
            float xin = (c == 0) ? v[j].x : (c == 1) ? v[j].y : (c == 2) ? v[j].z : v[j].w;
            float x    = (xin - mu) * rstd * lnw[idx] + lnb[idx];
            float prev = prev_row[idx];
            float mk = tmk[idx], mv = tmv[idx], mr = tmr[idx];
            ws[WS_XK + idx] = x * mk + prev * (1.0f - mk);
            ws[WS_XV + idx] = x * mv + prev * (1.0f - mv);
            ws[WS_XR + idx] = x * mr + prev * (1.0f - mr);
            x_row[idx] = x;
        }
    }
}

// Full-row dot for one wave: 16 float4 loads all issued before consumption.
// The asm memory fence stops the scheduler from sinking loads into the FMA loop.
__device__ __forceinline__ float row_dot_16(const float4* __restrict__ Wr,
                                            const float4* __restrict__ sx, int lane) {
    float4 w0  = Wr[ 0 * 64 + lane];
    float4 w1  = Wr[ 1 * 64 + lane];
    float4 w2  = Wr[ 2 * 64 + lane];
    float4 w3  = Wr[ 3 * 64 + lane];
    float4 w4  = Wr[ 4 * 64 + lane];
    float4 w5  = Wr[ 5 * 64 + lane];
    float4 w6  = Wr[ 6 * 64 + lane];
    float4 w7  = Wr[ 7 * 64 + lane];
    float4 w8  = Wr[ 8 * 64 + lane];
    float4 w9  = Wr[ 9 * 64 + lane];
    float4 w10 = Wr[10 * 64 + lane];
    float4 w11 = Wr[11 * 64 + lane];
    float4 w12 = Wr[12 * 64 + lane];
    float4 w13 = Wr[13 * 64 + lane];
    float4 w14 = Wr[14 * 64 + lane];
    float4 w15 = Wr[15 * 64 + lane];
    asm volatile("" ::: "memory");   // all 16 loads issued before any use below

    float acc0 = 0.0f, acc1 = 0.0f, acc2 = 0.0f, acc3 = 0.0f;
    #define DOT(ACC, W, I) { float4 x_ = sx[(I) * 64 + lane]; \
        ACC += (W).x*x_.x + (W).y*x_.y + (W).z*x_.z + (W).w*x_.w; }
    DOT(acc0, w0,  0)  DOT(acc1, w1,  1)  DOT(acc2, w2,  2)  DOT(acc3, w3,  3)
    DOT(acc0, w4,  4)  DOT(acc1, w5,  5)  DOT(acc2, w6,  6)  DOT(acc3, w7,  7)
    DOT(acc0, w8,  8)  DOT(acc1, w9,  9)  DOT(acc2, w10, 10) DOT(acc3, w11, 11)
    DOT(acc0, w12, 12) DOT(acc1, w13, 13) DOT(acc2, w14, 14) DOT(acc3, w15, 15)
    #undef DOT
    return (acc0 + acc1) + (acc2 + acc3);
}

// ---------------- kernel 2: fused 3-matrix matvec ----------------
// One wave per row; x staged in LDS; full 16KB row in flight per wave.
// __launch_bounds__(256,4): <=128 VGPR, 4 blocks (16 waves) per CU.
__global__ void __launch_bounds__(256, 4)
k_matvec3(const float* __restrict__ kw, const float* __restrict__ vw,
          const float* __restrict__ rw, const float* __restrict__ ws_in,
          float* __restrict__ ws_out) {
    __shared__ float4 sx[NE / 4];           // 16 KB
    int t    = threadIdx.x;
    int lane = t & 63;
    int gw   = blockIdx.x * 4 + (t >> 6);
    int m    = gw >> 12;
    int row  = gw & (NE - 1);
    const float* W = (m == 0) ? kw : (m == 1) ? vw : rw;
    const float4* xg = (const float4*)(ws_in + m * NE);
    #pragma unroll
    for (int j = 0; j < 4; ++j) sx[t + j * 256] = xg[t + j * 256];
    __syncthreads();

    const float4* Wr = (const float4*)(W + (size_t)row * NE);
    float a = row_dot_16(Wr, sx, lane);
    a = wave_reduce_sum(a);
    if (lane == 0) {
        if (m == 2) a = 1.0f / (1.0f + expf(-a));   // sigmoid on r path
        ws_out[m * NE + row] = a;
    }
}

// ---------------- kernel 3: WKV elementwise + state update ----------------
__global__ void k_wkv(const float* __restrict__ state, const float* __restrict__ tf,
                      const float* __restrict__ td, const int* __restrict__ layer,
                      const float* __restrict__ ws, float* __restrict__ out_state,
                      float* __restrict__ rwkv) {
    int idx = blockIdx.x * blockDim.x + threadIdx.x;
    if (idx >= NE) return;
    int li = layer[0];
    float kk = ws[WS_KK + idx];
    float vv = ws[WS_VV + idx];
    float r  = ws[WS_RR + idx];
    float aa = state[(size_t)(5 * li + 2) * NE + idx];
    float bb = state[(size_t)(5 * li + 3) * NE + idx];
    float pp = state[(size_t)(5 * li + 4) * NE + idx];

    float ww = tf[idx] + kk;
    float p  = fmaxf(pp, ww);
    float e1 = expf(pp - p);
    float e2 = expf(ww - p);
    float a  = e1 * aa + e2 * vv;
    float b  = e1 * bb + e2;

    float ww2 = pp + td[idx];
    float p2  = fmaxf(ww2, kk);
    float e1s = expf(ww2 - p2);
    float e2s = expf(kk - p2);
    out_state[(size_t)(5 * li + 2) * NE + idx] = e1s * aa + e2s * vv;
    out_state[(size_t)(5 * li + 3) * NE + idx] = e1s * bb + e2s;
    out_state[(size_t)(5 * li + 4) * NE + idx] = p2;

    rwkv[idx] = r * (a / b);
}

// ---------------- kernel 4: output matvec ----------------
__global__ void __launch_bounds__(256, 4)
k_matvec_ow(const float* __restrict__ ow, const float* __restrict__ rwkv,
            float* __restrict__ out) {
    __shared__ float4 sx[NE / 4];           // 16 KB
    int t    = threadIdx.x;
    int lane = t & 63;
    int row  = blockIdx.x * 4 + (t >> 6);
    const float4* xg = (const float4*)rwkv;
    #pragma unroll
    for (int j = 0; j < 4; ++j) sx[t + j * 256] = xg[t + j * 256];
    __syncthreads();

    const float4* Wr = (const float4*)(ow + (size_t)row * NE);
    float a = row_dot_16(Wr, sx, lane);
    a = wave_reduce_sum(a);
    if (lane == 0) out[row] = a;
}

extern "C" void kernel_launch(void* const* d_in, const int* in_sizes, int n_in,
                              void* d_out, int out_size, void* d_ws, size_t ws_size,
                              hipStream_t stream) {
    const float* input = (const float*)d_in[0];
    const float* state = (const float*)d_in[1];
    const float* tmk   = (const float*)d_in[2];
    const float* tmv   = (const float*)d_in[3];
    const float* tmr   = (const float*)d_in[4];
    const float* tf    = (const float*)d_in[5];
    const float* td    = (const float*)d_in[6];
    const float* kw    = (const float*)d_in[7];
    const float* vw    = (const float*)d_in[8];
    const float* rw    = (const float*)d_in[9];
    const float* ow    = (const float*)d_in[10];
    const float* lnw   = (const float*)d_in[11];
    const float* lnb   = (const float*)d_in[12];
    const int*   layer = (const int*)d_in[13];

    float* out_state = (float*)d_out;                            // 160*4096 floats
    float* out_vec   = (float*)d_out + (size_t)NROWS_STATE * NE; // 4096 floats
    float* ws        = (float*)d_ws;

    // 1. state copy (skips rows written later) + layernorm + time-mix
    k_copy_ln_mix<<<641, 256, 0, stream>>>(input, state, tmk, tmv, tmr, lnw, lnb,
                                           layer, out_state, ws);
    // 2. kk / vv / r matvecs — one wave per row, full row in flight
    k_matvec3<<<3 * NE / 4, 256, 0, stream>>>(kw, vw, rw, ws, ws + WS_KK);
    // 3. WKV recurrence
    k_wkv<<<NE / 256, 256, 0, stream>>>(state, tf, td, layer, ws, out_state,
                                        ws + WS_RWKV);
    // 4. out = ow @ (r * wkv)
    k_matvec_ow<<<NE / 4, 256, 0, stream>>>(ow, ws + WS_RWKV, out_vec);
}

// Round 5
// 57.976 us; speedup vs baseline: 1.0082x; 1.0082x over previous
//
#include <hip/hip_runtime.h>
#include <math.h>

#define NE 4096
#define NROWS_STATE 160   // 5 * 32 layers

// ws layout (floats)
#define WS_XK   0
#define WS_XV   (NE)
#define WS_XR   (2*NE)
#define WS_KK   (3*NE)
#define WS_VV   (4*NE)
#define WS_RR   (5*NE)
#define WS_RWKV (6*NE)

__device__ __forceinline__ float wave_reduce_sum(float v) {
    #pragma unroll
    for (int off = 32; off > 0; off >>= 1)
        v += __shfl_down(v, off, 64);
    return v;  // valid in lane 0
}

// Volatile inline-asm 16B global load: scheduler cannot sink or re-roll it.
__device__ __forceinline__ float4 gload4(const float4* p) {
    float4 r;
    asm volatile("global_load_dwordx4 %0, %1, off"
                 : "=v"(r) : "v"(p));
    return r;
}

// ---------------- kernel 1: state copy (skipping written rows) + LN + time-mix ----------------
__global__ void __launch_bounds__(256)
k_copy_ln_mix(const float* __restrict__ in, const float* __restrict__ state,
              const float* __restrict__ tmk, const float* __restrict__ tmv,
              const float* __restrict__ tmr, const float* __restrict__ lnw,
              const float* __restrict__ lnb, const int* __restrict__ layer,
              float* __restrict__ out_state, float* __restrict__ ws) {
    int li = layer[0];
    if (blockIdx.x != 0) {
        int i4 = (blockIdx.x - 1) * 256 + threadIdx.x;   // float4 index, 1024 per row
        int row = i4 >> 10;
        if (row < 5 * li + 1 || row > 5 * li + 4) {
            ((float4*)out_state)[i4] = ((const float4*)state)[i4];
        }
        return;
    }
    __shared__ float sm1[4];
    __shared__ float sm2[4];
    __shared__ float s_mu, s_rstd;
    int t = threadIdx.x;
    int lane = t & 63, wid = t >> 6;

    float4 v[4];
    float sum = 0.0f, sumsq = 0.0f;
    #pragma unroll
    for (int j = 0; j < 4; ++j) {
        v[j] = ((const float4*)in)[t * 4 + j];
        sum   += v[j].x + v[j].y + v[j].z + v[j].w;
        sumsq += v[j].x*v[j].x + v[j].y*v[j].y + v[j].z*v[j].z + v[j].w*v[j].w;
    }
    float s1 = wave_reduce_sum(sum);
    float s2 = wave_reduce_sum(sumsq);
    if (lane == 0) { sm1[wid] = s1; sm2[wid] = s2; }
    __syncthreads();
    if (t == 0) {
        float tot = sm1[0] + sm1[1] + sm1[2] + sm1[3];
        float tot2 = sm2[0] + sm2[1] + sm2[2] + sm2[3];
        float mu  = tot * (1.0f / NE);
        float var = tot2 * (1.0f / NE) - mu * mu;
        s_mu = mu;
        s_rstd = rsqrtf(var + 1e-5f);
    }
    __syncthreads();
    float mu = s_mu, rstd = s_rstd;

    const float* prev_row = state + (size_t)(5 * li + 1) * NE;
    float* x_row = out_state + (size_t)(5 * li + 1) * NE;

    #pragma unroll
    for (int j = 0; j < 4; ++j) {
        #pragma unroll
        for (int c = 0; c < 4; ++c) {
            int idx = t * 16 + j * 4 + c;
            float xin = (c == 0) ? v[j].x : (c == 1) ? v[j].y : (c == 2) ? v[j].z : v[j].w;
            float x    = (xin - mu) * rstd * lnw[idx] + lnb[idx];
            float prev = prev_row[idx];
            float mk = tmk[idx], mv = tmv[idx], mr = tmr[idx];
            ws[WS_XK + idx] = x * mk + prev * (1.0f - mk);
            ws[WS_XV + idx] = x * mv + prev * (1.0f - mv);
            ws[WS_XR + idx] = x * mr + prev * (1.0f - mr);
            x_row[idx] = x;
        }
    }
}

// Full-row dot: 16 volatile global_load_dwordx4 issued back-to-back (16KB in
// flight per wave), one vmcnt(0), sched_barrier so FMAs can't hoist past it.
__device__ __forceinline__ float row_dot_16(const float4* __restrict__ Wr,
                                            const float4* __restrict__ sx, int lane) {
    float4 w0  = gload4(Wr +  0 * 64 + lane);
    float4 w1  = gload4(Wr +  1 * 64 + lane);
    float4 w2  = gload4(Wr +  2 * 64 + lane);
    float4 w3  = gload4(Wr +  3 * 64 + lane);
    float4 w4  = gload4(Wr +  4 * 64 + lane);
    float4 w5  = gload4(Wr +  5 * 64 + lane);
    float4 w6  = gload4(Wr +  6 * 64 + lane);
    float4 w7  = gload4(Wr +  7 * 64 + lane);
    float4 w8  = gload4(Wr +  8 * 64 + lane);
    float4 w9  = gload4(Wr +  9 * 64 + lane);
    float4 w10 = gload4(Wr + 10 * 64 + lane);
    float4 w11 = gload4(Wr + 11 * 64 + lane);
    float4 w12 = gload4(Wr + 12 * 64 + lane);
    float4 w13 = gload4(Wr + 13 * 64 + lane);
    float4 w14 = gload4(Wr + 14 * 64 + lane);
    float4 w15 = gload4(Wr + 15 * 64 + lane);
    asm volatile("s_waitcnt vmcnt(0)" ::: "memory");
    __builtin_amdgcn_sched_barrier(0);

    float acc0 = 0.0f, acc1 = 0.0f, acc2 = 0.0f, acc3 = 0.0f;
    #define DOT(ACC, W, I) { float4 x_ = sx[(I) * 64 + lane]; \
        ACC += (W).x*x_.x + (W).y*x_.y + (W).z*x_.z + (W).w*x_.w; }
    DOT(acc0, w0,  0)  DOT(acc1, w1,  1)  DOT(acc2, w2,  2)  DOT(acc3, w3,  3)
    DOT(acc0, w4,  4)  DOT(acc1, w5,  5)  DOT(acc2, w6,  6)  DOT(acc3, w7,  7)
    DOT(acc0, w8,  8)  DOT(acc1, w9,  9)  DOT(acc2, w10, 10) DOT(acc3, w11, 11)
    DOT(acc0, w12, 12) DOT(acc1, w13, 13) DOT(acc2, w14, 14) DOT(acc3, w15, 15)
    #undef DOT
    return (acc0 + acc1) + (acc2 + acc3);
}

// ---------------- kernel 2: fused 3-matrix matvec ----------------
// One wave per row; x staged in LDS; full 16KB row in flight per wave.
__global__ void __launch_bounds__(256, 4)
k_matvec3(const float* __restrict__ kw, const float* __restrict__ vw,
          const float* __restrict__ rw, const float* __restrict__ ws_in,
          float* __restrict__ ws_out) {
    __shared__ float4 sx[NE / 4];           // 16 KB
    int t    = threadIdx.x;
    int lane = t & 63;
    int gw   = blockIdx.x * 4 + (t >> 6);
    int m    = gw >> 12;
    int row  = gw & (NE - 1);
    const float* W = (m == 0) ? kw : (m == 1) ? vw : rw;
    const float4* xg = (const float4*)(ws_in + m * NE);
    #pragma unroll
    for (int j = 0; j < 4; ++j) sx[t + j * 256] = xg[t + j * 256];
    __syncthreads();

    const float4* Wr = (const float4*)(W + (size_t)row * NE);
    float a = row_dot_16(Wr, sx, lane);
    a = wave_reduce_sum(a);
    if (lane == 0) {
        if (m == 2) a = 1.0f / (1.0f + expf(-a));   // sigmoid on r path
        ws_out[m * NE + row] = a;
    }
}

// ---------------- kernel 3: WKV elementwise + state update ----------------
__global__ void k_wkv(const float* __restrict__ state, const float* __restrict__ tf,
                      const float* __restrict__ td, const int* __restrict__ layer,
                      const float* __restrict__ ws, float* __restrict__ out_state,
                      float* __restrict__ rwkv) {
    int idx = blockIdx.x * blockDim.x + threadIdx.x;
    if (idx >= NE) return;
    int li = layer[0];
    float kk = ws[WS_KK + idx];
    float vv = ws[WS_VV + idx];
    float r  = ws[WS_RR + idx];
    float aa = state[(size_t)(5 * li + 2) * NE + idx];
    float bb = state[(size_t)(5 * li + 3) * NE + idx];
    float pp = state[(size_t)(5 * li + 4) * NE + idx];

    float ww = tf[idx] + kk;
    float p  = fmaxf(pp, ww);
    float e1 = expf(pp - p);
    float e2 = expf(ww - p);
    float a  = e1 * aa + e2 * vv;
    float b  = e1 * bb + e2;

    float ww2 = pp + td[idx];
    float p2  = fmaxf(ww2, kk);
    float e1s = expf(ww2 - p2);
    float e2s = expf(kk - p2);
    out_state[(size_t)(5 * li + 2) * NE + idx] = e1s * aa + e2s * vv;
    out_state[(size_t)(5 * li + 3) * NE + idx] = e1s * bb + e2s;
    out_state[(size_t)(5 * li + 4) * NE + idx] = p2;

    rwkv[idx] = r * (a / b);
}

// ---------------- kernel 4: output matvec ----------------
__global__ void __launch_bounds__(256, 4)
k_matvec_ow(const float* __restrict__ ow, const float* __restrict__ rwkv,
            float* __restrict__ out) {
    __shared__ float4 sx[NE / 4];           // 16 KB
    int t    = threadIdx.x;
    int lane = t & 63;
    int row  = blockIdx.x * 4 + (t >> 6);
    const float4* xg = (const float4*)rwkv;
    #pragma unroll
    for (int j = 0; j < 4; ++j) sx[t + j * 256] = xg[t + j * 256];
    __syncthreads();

    const float4* Wr = (const float4*)(ow + (size_t)row * NE);
    float a = row_dot_16(Wr, sx, lane);
    a = wave_reduce_sum(a);
    if (lane == 0) out[row] = a;
}

extern "C" void kernel_launch(void* const* d_in, const int* in_sizes, int n_in,
                              void* d_out, int out_size, void* d_ws, size_t ws_size,
                              hipStream_t stream) {
    const float* input = (const float*)d_in[0];
    const float* state = (const float*)d_in[1];
    const float* tmk   = (const float*)d_in[2];
    const float* tmv   = (const float*)d_in[3];
    const float* tmr   = (const float*)d_in[4];
    const float* tf    = (const float*)d_in[5];
    const float* td    = (const float*)d_in[6];
    const float* kw    = (const float*)d_in[7];
    const float* vw    = (const float*)d_in[8];
    const float* rw    = (const float*)d_in[9];
    const float* ow    = (const float*)d_in[10];
    const float* lnw   = (const float*)d_in[11];
    const float* lnb   = (const float*)d_in[12];
    const int*   layer = (const int*)d_in[13];

    float* out_state = (float*)d_out;                            // 160*4096 floats
    float* out_vec   = (float*)d_out + (size_t)NROWS_STATE * NE; // 4096 floats
    float* ws        = (float*)d_ws;

    // 1. state copy (skips rows written later) + layernorm + time-mix
    k_copy_ln_mix<<<641, 256, 0, stream>>>(input, state, tmk, tmv, tmr, lnw, lnb,
                                           layer, out_state, ws);
    // 2. kk / vv / r matvecs — one wave per row, full row in flight
    k_matvec3<<<3 * NE / 4, 256, 0, stream>>>(kw, vw, rw, ws, ws + WS_KK);
    // 3. WKV recurrence
    k_wkv<<<NE / 256, 256, 0, stream>>>(state, tf, td, layer, ws, out_state,
                                        ws + WS_RWKV);
    // 4. out = ow @ (r * wkv)
    k_matvec_ow<<<NE / 4, 256, 0, stream>>>(ow, ws + WS_RWKV, out_vec);
}

// Round 6
// 56.070 us; speedup vs baseline: 1.0424x; 1.0340x over previous
//
#include <hip/hip_runtime.h>
#include <math.h>

#define NE 4096
#define NROWS_STATE 160   // 5 * 32 layers

// ws layout (floats)
#define WS_XK   0
#define WS_XV   (NE)
#define WS_XR   (2*NE)
#define WS_KK   (3*NE)
#define WS_VV   (4*NE)
#define WS_RR   (5*NE)
#define WS_RWKV (6*NE)

__device__ __forceinline__ float wave_reduce_sum(float v) {
    #pragma unroll
    for (int off = 32; off > 0; off >>= 1)
        v += __shfl_down(v, off, 64);
    return v;  // valid in lane 0
}

// ---------------- kernel 1: state copy + accumulator zero + LN + time-mix ----------------
// block 0:        LN + mix (256 threads, 16 elems each)
// blocks 1..640:  copy state float4s, skipping rows 5i+1..5i+4
// blocks 641..656: zero the kk/vv/rr accumulators (3*NE) and out_vec (NE)
__global__ void __launch_bounds__(256)
k_copy_ln_mix(const float* __restrict__ in, const float* __restrict__ state,
              const float* __restrict__ tmk, const float* __restrict__ tmv,
              const float* __restrict__ tmr, const float* __restrict__ lnw,
              const float* __restrict__ lnb, const int* __restrict__ layer,
              float* __restrict__ out_state, float* __restrict__ out_vec,
              float* __restrict__ ws) {
    int li = layer[0];
    if (blockIdx.x >= 641) {
        // ---- zero accumulators ----
        int zidx = (blockIdx.x - 641) * 256 + threadIdx.x;    // float4 index 0..4095
        float4 z = make_float4(0.f, 0.f, 0.f, 0.f);
        if (zidx < 3 * NE / 4) ((float4*)(ws + WS_KK))[zidx] = z;
        else                   ((float4*)out_vec)[zidx - 3 * NE / 4] = z;
        return;
    }
    if (blockIdx.x != 0) {
        // ---- copy path ----
        int i4 = (blockIdx.x - 1) * 256 + threadIdx.x;   // float4 index, 1024 per row
        int row = i4 >> 10;
        if (row < 5 * li + 1 || row > 5 * li + 4) {
            ((float4*)out_state)[i4] = ((const float4*)state)[i4];
        }
        return;
    }
    // ---- LN + mix path (block 0) ----
    __shared__ float sm1[4];
    __shared__ float sm2[4];
    __shared__ float s_mu, s_rstd;
    int t = threadIdx.x;
    int lane = t & 63, wid = t >> 6;

    float4 v[4];
    float sum = 0.0f, sumsq = 0.0f;
    #pragma unroll
    for (int j = 0; j < 4; ++j) {
        v[j] = ((const float4*)in)[t * 4 + j];
        sum   += v[j].x + v[j].y + v[j].z + v[j].w;
        sumsq += v[j].x*v[j].x + v[j].y*v[j].y + v[j].z*v[j].z + v[j].w*v[j].w;
    }
    float s1 = wave_reduce_sum(sum);
    float s2 = wave_reduce_sum(sumsq);
    if (lane == 0) { sm1[wid] = s1; sm2[wid] = s2; }
    __syncthreads();
    if (t == 0) {
        float tot  = sm1[0] + sm1[1] + sm1[2] + sm1[3];
        float tot2 = sm2[0] + sm2[1] + sm2[2] + sm2[3];
        float mu  = tot * (1.0f / NE);
        float var = tot2 * (1.0f / NE) - mu * mu;
        s_mu = mu;
        s_rstd = rsqrtf(var + 1e-5f);
    }
    __syncthreads();
    float mu = s_mu, rstd = s_rstd;

    const float* prev_row = state + (size_t)(5 * li + 1) * NE;
    float* x_row = out_state + (size_t)(5 * li + 1) * NE;

    #pragma unroll
    for (int j = 0; j < 4; ++j) {
        #pragma unroll
        for (int c = 0; c < 4; ++c) {
            int idx = t * 16 + j * 4 + c;
            float xin = (c == 0) ? v[j].x : (c == 1) ? v[j].y : (c == 2) ? v[j].z : v[j].w;
            float x    = (xin - mu) * rstd * lnw[idx] + lnb[idx];
            float prev = prev_row[idx];
            float mk = tmk[idx], mv = tmv[idx], mr = tmr[idx];
            ws[WS_XK + idx] = x * mk + prev * (1.0f - mk);
            ws[WS_XV + idx] = x * mv + prev * (1.0f - mv);
            ws[WS_XR + idx] = x * mr + prev * (1.0f - mr);
            x_row[idx] = x;
        }
    }
}

// ---------------- kernel 2: fused 3-matrix matvec, segment-parallel ----------------
// 4 segments per row, one wave per (matrix,row,segment): 49152 waves, 12288 blocks.
// Copy-benchmark shape: short waves, rolled loads, no LDS, atomic accumulate.
__global__ void __launch_bounds__(256)
k_matvec3(const float* __restrict__ kw, const float* __restrict__ vw,
          const float* __restrict__ rw, const float* __restrict__ ws_in,
          float* __restrict__ ws_out) {
    int t    = threadIdx.x;
    int lane = t & 63;
    int g    = blockIdx.x * 4 + (t >> 6);   // global wave id
    int m    = g >> 14;                      // 16384 waves per matrix
    int rem  = g & 16383;
    int row  = rem >> 2;
    int seg  = rem & 3;
    const float* W = (m == 0) ? kw : (m == 1) ? vw : rw;
    const float4* Wr = (const float4*)(W + (size_t)row * NE) + seg * 256;
    const float4* xv = (const float4*)(ws_in + m * NE) + seg * 256;

    float acc = 0.0f;
    #pragma unroll
    for (int i = 0; i < 4; ++i) {
        float4 w4 = Wr[i * 64 + lane];
        float4 x4 = xv[i * 64 + lane];
        acc += w4.x*x4.x + w4.y*x4.y + w4.z*x4.z + w4.w*x4.w;
    }
    acc = wave_reduce_sum(acc);
    if (lane == 0) atomicAdd(&ws_out[m * NE + row], acc);
}

// ---------------- kernel 3: WKV elementwise + state update (sigmoid folded in) ----------------
__global__ void k_wkv(const float* __restrict__ state, const float* __restrict__ tf,
                      const float* __restrict__ td, const int* __restrict__ layer,
                      const float* __restrict__ ws, float* __restrict__ out_state,
                      float* __restrict__ rwkv) {
    int idx = blockIdx.x * blockDim.x + threadIdx.x;
    if (idx >= NE) return;
    int li = layer[0];
    float kk = ws[WS_KK + idx];
    float vv = ws[WS_VV + idx];
    float r  = 1.0f / (1.0f + expf(-ws[WS_RR + idx]));   // sigmoid here now
    float aa = state[(size_t)(5 * li + 2) * NE + idx];
    float bb = state[(size_t)(5 * li + 3) * NE + idx];
    float pp = state[(size_t)(5 * li + 4) * NE + idx];

    float ww = tf[idx] + kk;
    float p  = fmaxf(pp, ww);
    float e1 = expf(pp - p);
    float e2 = expf(ww - p);
    float a  = e1 * aa + e2 * vv;
    float b  = e1 * bb + e2;

    float ww2 = pp + td[idx];
    float p2  = fmaxf(ww2, kk);
    float e1s = expf(ww2 - p2);
    float e2s = expf(kk - p2);
    out_state[(size_t)(5 * li + 2) * NE + idx] = e1s * aa + e2s * vv;
    out_state[(size_t)(5 * li + 3) * NE + idx] = e1s * bb + e2s;
    out_state[(size_t)(5 * li + 4) * NE + idx] = p2;

    rwkv[idx] = r * (a / b);
}

// ---------------- kernel 4: output matvec, segment-parallel ----------------
// 4 segments per row: 16384 waves, 4096 blocks. out_vec pre-zeroed in kernel 1.
__global__ void __launch_bounds__(256)
k_matvec_ow(const float* __restrict__ ow, const float* __restrict__ rwkv,
            float* __restrict__ out) {
    int t    = threadIdx.x;
    int lane = t & 63;
    int g    = blockIdx.x * 4 + (t >> 6);
    int row  = g >> 2;
    int seg  = g & 3;
    const float4* Wr = (const float4*)(ow + (size_t)row * NE) + seg * 256;
    const float4* xv = (const float4*)rwkv + seg * 256;

    float acc = 0.0f;
    #pragma unroll
    for (int i = 0; i < 4; ++i) {
        float4 w4 = Wr[i * 64 + lane];
        float4 x4 = xv[i * 64 + lane];
        acc += w4.x*x4.x + w4.y*x4.y + w4.z*x4.z + w4.w*x4.w;
    }
    acc = wave_reduce_sum(acc);
    if (lane == 0) atomicAdd(&out[row], acc);
}

extern "C" void kernel_launch(void* const* d_in, const int* in_sizes, int n_in,
                              void* d_out, int out_size, void* d_ws, size_t ws_size,
                              hipStream_t stream) {
    const float* input = (const float*)d_in[0];
    const float* state = (const float*)d_in[1];
    const float* tmk   = (const float*)d_in[2];
    const float* tmv   = (const float*)d_in[3];
    const float* tmr   = (const float*)d_in[4];
    const float* tf    = (const float*)d_in[5];
    const float* td    = (const float*)d_in[6];
    const float* kw    = (const float*)d_in[7];
    const float* vw    = (const float*)d_in[8];
    const float* rw    = (const float*)d_in[9];
    const float* ow    = (const float*)d_in[10];
    const float* lnw   = (const float*)d_in[11];
    const float* lnb   = (const float*)d_in[12];
    const int*   layer = (const int*)d_in[13];

    float* out_state = (float*)d_out;                            // 160*4096 floats
    float* out_vec   = (float*)d_out + (size_t)NROWS_STATE * NE; // 4096 floats
    float* ws        = (float*)d_ws;

    // 1. state copy + accumulator zeroing + layernorm + time-mix
    k_copy_ln_mix<<<657, 256, 0, stream>>>(input, state, tmk, tmv, tmr, lnw, lnb,
                                           layer, out_state, out_vec, ws);
    // 2. kk / vv / rr matvecs — 4 waves per row, atomic accumulate
    k_matvec3<<<3 * NE, 256, 0, stream>>>(kw, vw, rw, ws, ws + WS_KK);
    // 3. WKV recurrence (+ sigmoid of rr)
    k_wkv<<<NE / 256, 256, 0, stream>>>(state, tf, td, layer, ws, out_state,
                                        ws + WS_RWKV);
    // 4. out = ow @ (r * wkv) — 4 waves per row, atomic accumulate
    k_matvec_ow<<<NE, 256, 0, stream>>>(ow, ws + WS_RWKV, out_vec);
}